// Round 17
// baseline (43.885 us; speedup 1.0000x reference)
//
#include <hip/hip_runtime.h>
#include <math.h>

typedef __bf16 bf16x8 __attribute__((ext_vector_type(8)));
typedef float f32x4 __attribute__((ext_vector_type(4)));

#define B_SZ 512
#define IN_F 342
#define HID  512
#define OUT_F 311

// ---------------------------------------------------------------------------
// Weight transpose+convert+interleave (one 64x64 tile per call):
//  JOB0: T0[h*4+c][i] = W0[c][i][h]  (2048 x 384, i>=342 -> 0)
//  JOB1: T1[h*4+c][k] = W1[c][k][h]  (2048 x 512)
//  JOB2: T2[n*4+c][k] = W2[c][k][n]  (1280 x 512, n>=311 -> 0)
// Interleaved rows n'=h*4+c put the 4 c-slices of an output in one MFMA
// lane-quad -> coefficient reduction is 2 shfl_xor in the GEMM epilogue.
// ---------------------------------------------------------------------------
template <int JOB>
__device__ void wt_transpose(const float* __restrict__ W, __bf16* __restrict__ T,
                             int t) {
  constexpr int KP   = (JOB == 0) ? 384 : 512;   // dest row length (padded k)
  constexpr int KWF  = (JOB == 0) ? IN_F : HID;  // W k extent
  constexpr int NC   = (JOB == 2) ? OUT_F : HID; // W col extent
  constexpr int NSUB = (JOB == 2) ? 320 : 512;   // dest rows per c (pre-ilv)
  constexpr int KT   = KP / 64;
  const int r0 = (t / KT) * 64, k0 = (t % KT) * 64;
  __shared__ __bf16 tile[64][66];
  const int tid = threadIdx.x;
  const int rl = tid & 63;
  const int c = r0 / NSUB;          // uniform per tile (64 | NSUB)
  const int nbase = r0 - c * NSUB;
#pragma unroll
  for (int jj = 0; jj < 16; ++jj) {
    int kl = (tid >> 6) + jj * 4;
    int k = k0 + kl;
    int n = nbase + rl;
    float v = 0.0f;
    if ((JOB != 0 || k < KWF) && (JOB != 2 || n < NC))
      v = W[((size_t)c * KWF + k) * NC + n];
    tile[rl][kl] = (__bf16)v;
  }
  __syncthreads();
  int row = tid >> 2, o0 = (tid & 3) * 16;
  bf16x8 v0 = *(const bf16x8*)&tile[row][o0];
  bf16x8 v1 = *(const bf16x8*)&tile[row][o0 + 8];
  int g = (nbase + row) * 4 + c;    // interleaved dest row
  __bf16* dst = T + (size_t)g * KP + k0 + o0;
  *(bf16x8*)dst = v0;
  *(bf16x8*)(dst + 8) = v1;
}

// ---------------------------------------------------------------------------
// Barrier-free GEMM: 32x32 output block; A-stripe and B-panel FULLY resident
// in LDS. Prologue: one burst of b128 loads (all outstanding) -> LDS -> ONE
// barrier -> pure ds_read+MFMA (no further syncs). 4 waves 2x2, wave tile
// 16x16, K-chain = KA/32 accumulating MFMAs. Quad-reduce epilogue over
// interleaved c (R12/R15-validated).
// ---------------------------------------------------------------------------
template <int LAYER>
__device__ void gemm_body(int nx, int my, const __bf16* __restrict__ A,
                          const __bf16* __restrict__ BT,
                          const float* __restrict__ bias,
                          const float* __restrict__ coef,
                          void* __restrict__ outv) {
  constexpr int KA = (LAYER == 0) ? 384 : 512;
  constexpr int NL = KA / 64;       // b128 loads per operand per thread (6/8)
  constexpr int LDK = KA + 8;       // row stride: +8 elems -> 4-bank rotate
  __shared__ __bf16 Als[32 * LDK];
  __shared__ __bf16 Bls[32 * LDK];

  const int tid = threadIdx.x;
  const int l = tid & 63;
  const int wave = tid >> 6;
  const int wm = wave >> 1, wn = wave & 1;
  const int lr = l & 15, lk = l >> 4;
  const int m0 = my * 32;
  const int n0 = nx * 32;

  // staging: thread -> row (0..31), octet chain o_, o_+8, ...
  const int r_ = tid >> 3;
  const int o_ = tid & 7;
  const __bf16* Ap = A + (size_t)(m0 + r_) * KA + o_ * 8;
  const __bf16* Bp = BT + (size_t)(n0 + r_) * KA + o_ * 8;

  bf16x8 av[NL], bv[NL];
#pragma unroll
  for (int j = 0; j < NL; ++j) av[j] = *(const bf16x8*)&Ap[j * 64];
#pragma unroll
  for (int j = 0; j < NL; ++j) bv[j] = *(const bf16x8*)&Bp[j * 64];
#pragma unroll
  for (int j = 0; j < NL; ++j)
    *(bf16x8*)&Als[r_ * LDK + o_ * 8 + j * 64] = av[j];
#pragma unroll
  for (int j = 0; j < NL; ++j)
    *(bf16x8*)&Bls[r_ * LDK + o_ * 8 + j * 64] = bv[j];
  __syncthreads();   // the ONLY barrier

  f32x4 acc = {};
#pragma unroll
  for (int kk = 0; kk < KA; kk += 32) {
    bf16x8 af = *(const bf16x8*)&Als[(wm * 16 + lr) * LDK + kk + lk * 8];
    bf16x8 bg = *(const bf16x8*)&Bls[(wn * 16 + lr) * LDK + kk + lk * 8];
    acc = __builtin_amdgcn_mfma_f32_16x16x32_bf16(af, bg, acc, 0, 0, 0);
  }

  // ---- fused epilogue: quad holds the 4 c-partials of (gm, hn) ----
  const int cl = l & 3;
  int gnp = n0 + wn * 16 + lr;
  int hn = gnp >> 2;                         // h (L0/L1) or n (L2)
  float bv_;
  if (LAYER == 2) bv_ = (hn < OUT_F) ? bias[cl * OUT_F + hn] : 0.0f;
  else            bv_ = bias[cl * HID + hn];
#pragma unroll
  for (int r = 0; r < 4; ++r) {
    int gm = m0 + wm * 16 + lk * 4 + r;
    float cf = coef[gm * 4 + cl];
    float v = cf * (acc[r] + bv_);
    v += __shfl_xor(v, 1);
    v += __shfl_xor(v, 2);                   // quad sum over c
    if (LAYER == 2) {
      if (cl == 0 && hn < OUT_F)
        ((float*)outv)[(size_t)gm * OUT_F + hn] = v;
    } else {
      if (cl == 0) {
        float e = (v > 0.0f) ? v : expm1f(v);
        ((__bf16*)outv)[(size_t)gm * HID + hn] = (__bf16)e;
      }
    }
  }
}

// ---------------------------------------------------------------------------
// setup (625 blocks, one job each — full-width BW burst):
//  0..191 WT0, 192..447 WT1, 448..607 WT2, 608..623 A0=bf16(x), 624 coef.
// ---------------------------------------------------------------------------
__global__ __launch_bounds__(256) void setup_kernel(
    const float* __restrict__ p, const float* __restrict__ x,
    const float* __restrict__ W0, const float* __restrict__ W1,
    const float* __restrict__ W2, float* __restrict__ coef,
    __bf16* __restrict__ A0, __bf16* __restrict__ T0,
    __bf16* __restrict__ T1, __bf16* __restrict__ T2) {
  int bid = blockIdx.x, tid = threadIdx.x;
  if (bid < 192)      { wt_transpose<0>(W0, T0, bid); return; }
  if (bid < 448)      { wt_transpose<1>(W1, T1, bid - 192); return; }
  if (bid < 608)      { wt_transpose<2>(W2, T2, bid - 448); return; }
  if (bid < 624) {
    int base = (bid - 608) * 32;
    for (int e = tid; e < 32 * 384; e += 256) {
      int m = base + e / 384, i = e - (e / 384) * 384;
      A0[(size_t)m * 384 + i] =
          (i < IN_F) ? (__bf16)x[(size_t)m * IN_F + i] : (__bf16)0.0f;
    }
    return;
  }
  for (int b = tid; b < B_SZ; b += 256) {
    float p4 = p[b] * 4.0f;
    float mu = p4 - floorf(p4);
    int i1 = ((int)p4) & 3;
    float mu2 = mu * mu, mu3 = mu2 * mu;
    float c0 = -0.5f * mu3 + mu2 - 0.5f * mu;
    float c1 =  1.5f * mu3 - 2.5f * mu2 + 1.0f;
    float c2 = -1.5f * mu3 + 2.0f * mu2 + 0.5f * mu;
    float c3 =  0.5f * mu3 - 0.5f * mu2;
    float arr[4];
    arr[(i1 + 3) & 3] = c0;
    arr[i1]           = c1;
    arr[(i1 + 1) & 3] = c2;
    arr[(i1 + 2) & 3] = c3;
    coef[b * 4 + 0] = arr[0];
    coef[b * 4 + 1] = arr[1];
    coef[b * 4 + 2] = arr[2];
    coef[b * 4 + 3] = arr[3];
  }
}

__global__ __launch_bounds__(256) void g0_kernel(
    const __bf16* __restrict__ A0, const __bf16* __restrict__ T0,
    const float* __restrict__ b0, const float* __restrict__ coef,
    __bf16* __restrict__ E1) {
  gemm_body<0>(blockIdx.x, blockIdx.y, A0, T0, b0, coef, E1);
}

__global__ __launch_bounds__(256) void g1_kernel(
    const __bf16* __restrict__ E1, const __bf16* __restrict__ T1,
    const float* __restrict__ b1, const float* __restrict__ coef,
    __bf16* __restrict__ E2) {
  gemm_body<1>(blockIdx.x, blockIdx.y, E1, T1, b1, coef, E2);
}

__global__ __launch_bounds__(256) void g2_kernel(
    const __bf16* __restrict__ E2, const __bf16* __restrict__ T2,
    const float* __restrict__ b2, const float* __restrict__ coef,
    float* __restrict__ out) {
  gemm_body<2>(blockIdx.x, blockIdx.y, E2, T2, b2, coef, out);
}

extern "C" void kernel_launch(void* const* d_in, const int* in_sizes, int n_in,
                              void* d_out, int out_size, void* d_ws, size_t ws_size,
                              hipStream_t stream) {
  const float* p  = (const float*)d_in[0];
  const float* x  = (const float*)d_in[1];
  const float* W0 = (const float*)d_in[2];
  const float* b0 = (const float*)d_in[3];
  const float* W1 = (const float*)d_in[4];
  const float* b1 = (const float*)d_in[5];
  const float* W2 = (const float*)d_in[6];
  const float* b2 = (const float*)d_in[7];
  float* out = (float*)d_out;

  char* w = (char*)d_ws;
  float*  coef = (float*)w;   w += 8192;
  __bf16* A0   = (__bf16*)w;  w += (size_t)B_SZ * 384 * 2;   // 384 KB
  __bf16* T0   = (__bf16*)w;  w += (size_t)2048 * 384 * 2;   // 1.5 MB
  __bf16* T1   = (__bf16*)w;  w += (size_t)2048 * 512 * 2;   // 2 MB
  __bf16* T2   = (__bf16*)w;  w += (size_t)1280 * 512 * 2;   // 1.25 MB
  __bf16* E1   = (__bf16*)w;  w += (size_t)B_SZ * HID * 2;   // 512 KB
  __bf16* E2   = (__bf16*)w;  w += (size_t)B_SZ * HID * 2;   // 512 KB

  setup_kernel<<<625, 256, 0, stream>>>(p, x, W0, W1, W2, coef, A0, T0, T1, T2);
  g0_kernel<<<dim3(64, 16), 256, 0, stream>>>(A0, T0, b0, coef, E1);
  g1_kernel<<<dim3(64, 16), 256, 0, stream>>>(E1, T1, b1, coef, E2);
  g2_kernel<<<dim3(40, 16), 256, 0, stream>>>(E2, T2, b2, coef, out);
}

// Round 18
// 40.771 us; speedup vs baseline: 1.0764x; 1.0764x over previous
//
#include <hip/hip_runtime.h>
#include <math.h>

typedef __bf16 bf16x8 __attribute__((ext_vector_type(8)));
typedef float f32x4 __attribute__((ext_vector_type(4)));

#define B_SZ 512
#define IN_F 342
#define HID  512
#define OUT_F 311
#define K0P  1536   // 4*IN_F = 1368 padded to multiple of 256
#define K12  2048   // 4*HID
#define N2P  320    // OUT_F padded
#define SPLIT 4

// ---------------------------------------------------------------------------
// setup (one launch, 1120 blocks):
//  blocks 0..511    : prep — coef[b][4] + layer-0 expanded bf16 input A0
//  blocks 512..1119 : weight transpose+convert W(KxN f32) -> WT(Np x Kp bf16)
// ---------------------------------------------------------------------------
__global__ __launch_bounds__(256) void setup_kernel(
    const float* __restrict__ p, const float* __restrict__ x,
    const float* __restrict__ W0, const float* __restrict__ W1,
    const float* __restrict__ W2, float* __restrict__ coef,
    __bf16* __restrict__ A0, __bf16* __restrict__ T0,
    __bf16* __restrict__ T1, __bf16* __restrict__ T2) {
  int bid = blockIdx.x;
  int tid = threadIdx.x;
  if (bid < B_SZ) {
    // ---- prep path ----
    int b = bid;
    __shared__ float cf[4];
    if (tid == 0) {
      float p4 = p[b] * 4.0f;
      float mu = p4 - floorf(p4);
      int i1 = ((int)p4) & 3;
      float mu2 = mu * mu, mu3 = mu2 * mu;
      float c0 = -0.5f * mu3 + mu2 - 0.5f * mu;
      float c1 =  1.5f * mu3 - 2.5f * mu2 + 1.0f;
      float c2 = -1.5f * mu3 + 2.0f * mu2 + 0.5f * mu;
      float c3 =  0.5f * mu3 - 0.5f * mu2;
      cf[(i1 + 3) & 3] = c0;
      cf[i1]           = c1;
      cf[(i1 + 1) & 3] = c2;
      cf[(i1 + 2) & 3] = c3;
    }
    __syncthreads();
    if (tid < 4) coef[b * 4 + tid] = cf[tid];
    float c0 = cf[0], c1 = cf[1], c2 = cf[2], c3 = cf[3];
    const float* xr = x + (size_t)b * IN_F;
    __bf16* dst = A0 + (size_t)b * K0P;
    for (int i = tid; i < IN_F; i += 256) {
      float xv = xr[i];
      dst[i]            = (__bf16)(c0 * xv);
      dst[IN_F + i]     = (__bf16)(c1 * xv);
      dst[2 * IN_F + i] = (__bf16)(c2 * xv);
      dst[3 * IN_F + i] = (__bf16)(c3 * xv);
    }
    for (int k = 4 * IN_F + tid; k < K0P; k += 256) dst[k] = (__bf16)0.0f;
    return;
  }
  // ---- transpose path ----
  bid -= B_SZ;
  const float* W; __bf16* T; int K, N, Kp, tk, t;
  if (bid < 192)      { W = W0; T = T0; K = 1368; N = 512; Kp = K0P; t = bid;       tk = 24; }
  else if (bid < 448) { W = W1; T = T1; K = 2048; N = 512; Kp = K12; t = bid - 192; tk = 32; }
  else                { W = W2; T = T2; K = 2048; N = 311; Kp = K12; t = bid - 448; tk = 32; }
  int k0 = (t % tk) * 64, n0 = (t / tk) * 64;
  __shared__ __bf16 tile[64][66];
  int nl = tid & 63, n = n0 + nl;
#pragma unroll
  for (int r = 0; r < 16; ++r) {
    int kl = (tid >> 6) + r * 4;
    int k = k0 + kl;
    float v = (k < K && n < N) ? W[(size_t)k * N + n] : 0.0f;
    tile[nl][kl] = (__bf16)v;
  }
  __syncthreads();
  int row = tid >> 2, o0 = (tid & 3) * 2;
  bf16x8 v0 = *(const bf16x8*)&tile[row][o0 * 8];
  bf16x8 v1 = *(const bf16x8*)&tile[row][o0 * 8 + 8];
  __bf16* dst = T + (size_t)(n0 + row) * Kp + k0 + o0 * 8;
  *(bf16x8*)dst = v0;
  *(bf16x8*)(dst + 8) = v1;
}

// ---------------------------------------------------------------------------
// Split-K bf16 MFMA GEMM, M-tile 32 for 2 blocks/CU TLP.
// A: M x Ka bf16; BT: Np x Ka bf16 (k-major); fully padded -> no bounds
// checks. Block (nx, my, z): 32x64 tile over K range [z*C,(z+1)*C), T=C/64
// even. 4 waves 2x2, wave tile 16x32 (1x2 frags of 16x16x32), BK=64, 2-deep
// reg prefetch with statically-named phase buffers (rule #20).
// Writes fp32 partials P[z][M][Np].
// ---------------------------------------------------------------------------
__global__ __launch_bounds__(256) void gemm_splitk(
    const __bf16* __restrict__ A, const __bf16* __restrict__ BT,
    float* __restrict__ P, int Ka, int Np, int C) {
  constexpr int LDT = 72;
  __shared__ __bf16 Als[32 * LDT];
  __shared__ __bf16 Bls[64 * LDT];

  const int tid = threadIdx.x;
  const int l = tid & 63;
  const int wave = tid >> 6;
  const int wm = wave >> 1, wn = wave & 1;
  const int lr = l & 15, lk = l >> 4;
  const int m0 = blockIdx.y * 32;
  const int n0 = blockIdx.x * 64;
  const int kbase = blockIdx.z * C;
  const int T = C >> 6;

  // A staging: row ar (0..31), one octet ao (0..7)
  const int ar = tid >> 3;
  const int ao = tid & 7;
  // B staging: row br (0..63), two octets starting at bo
  const int br = tid >> 2;
  const int bo = (tid & 3) * 2;

  const __bf16* Ap = A + (size_t)(m0 + ar) * Ka + kbase + ao * 8;
  const __bf16* Bp = BT + (size_t)(n0 + br) * Ka + kbase + bo * 8;

  bf16x8 a0_, b0_, b1_;   // phase 0
  bf16x8 a1_, b2_, b3_;   // phase 1
  f32x4 acc[2] = {};

  auto load0 = [&](int t) {
    a0_ = *(const bf16x8*)&Ap[t * 64];
    b0_ = *(const bf16x8*)&Bp[t * 64];
    b1_ = *(const bf16x8*)&Bp[t * 64 + 8];
  };
  auto load1 = [&](int t) {
    a1_ = *(const bf16x8*)&Ap[t * 64];
    b2_ = *(const bf16x8*)&Bp[t * 64];
    b3_ = *(const bf16x8*)&Bp[t * 64 + 8];
  };
  auto store0 = [&]() {
    *(bf16x8*)&Als[ar * LDT + ao * 8] = a0_;
    *(bf16x8*)&Bls[br * LDT + bo * 8] = b0_;
    *(bf16x8*)&Bls[br * LDT + bo * 8 + 8] = b1_;
  };
  auto store1 = [&]() {
    *(bf16x8*)&Als[ar * LDT + ao * 8] = a1_;
    *(bf16x8*)&Bls[br * LDT + bo * 8] = b2_;
    *(bf16x8*)&Bls[br * LDT + bo * 8 + 8] = b3_;
  };
  auto compute = [&]() {
#pragma unroll
    for (int kk = 0; kk < 64; kk += 32) {
      bf16x8 af = *(const bf16x8*)&Als[(wm * 16 + lr) * LDT + kk + lk * 8];
      bf16x8 bg[2];
#pragma unroll
      for (int j = 0; j < 2; ++j)
        bg[j] = *(const bf16x8*)&Bls[(wn * 32 + j * 16 + lr) * LDT + kk + lk * 8];
#pragma unroll
      for (int j = 0; j < 2; ++j)
        acc[j] = __builtin_amdgcn_mfma_f32_16x16x32_bf16(af, bg[j], acc[j], 0, 0, 0);
    }
  };

  load0(0);
  load1(1);
  for (int t = 0; t < T; t += 2) {
    __syncthreads();
    store0();
    __syncthreads();
    if (t + 2 < T) load0(t + 2);
    compute();
    __syncthreads();
    store1();
    __syncthreads();
    if (t + 3 < T) load1(t + 3);
    compute();
  }

  float* Pp = P + (size_t)blockIdx.z * B_SZ * Np;
#pragma unroll
  for (int j = 0; j < 2; ++j) {
    int gn = n0 + wn * 32 + j * 16 + lr;
#pragma unroll
    for (int r = 0; r < 4; ++r) {
      int gm = m0 + wm * 16 + lk * 4 + r;
      Pp[(size_t)gm * Np + gn] = acc[j][r];
    }
  }
}

// ---------------------------------------------------------------------------
// epilogue: v = sum_s P[s][m][n] + bias_interp; EXPAND: ELU + 4 scaled bf16
// copies into A_next[m][c*N + n]; else fp32 out[m][n] (n < N only).
// ---------------------------------------------------------------------------
template <int EXPAND, int NP>
__global__ __launch_bounds__(256) void epilogue_kernel(
    const float* __restrict__ P, const float* __restrict__ bias,
    const float* __restrict__ coef, void* __restrict__ outv, int N) {
  int idx = blockIdx.x * 256 + threadIdx.x;
  int m = idx / NP, n = idx - m * NP;
  if (m >= B_SZ || n >= N) return;
  float v = P[idx] + P[idx + B_SZ * NP] + P[idx + 2 * B_SZ * NP] +
            P[idx + 3 * B_SZ * NP];
  f32x4 cf = *(const f32x4*)&coef[m * 4];
  v += cf[0] * bias[n] + cf[1] * bias[N + n] + cf[2] * bias[2 * N + n] +
       cf[3] * bias[3 * N + n];
  if (EXPAND) {
    v = (v > 0.0f) ? v : expm1f(v);
    __bf16* dst = (__bf16*)outv + (size_t)m * (4 * N) + n;
    dst[0]     = (__bf16)(cf[0] * v);
    dst[N]     = (__bf16)(cf[1] * v);
    dst[2 * N] = (__bf16)(cf[2] * v);
    dst[3 * N] = (__bf16)(cf[3] * v);
  } else {
    ((float*)outv)[(size_t)m * N + n] = v;
  }
}

extern "C" void kernel_launch(void* const* d_in, const int* in_sizes, int n_in,
                              void* d_out, int out_size, void* d_ws, size_t ws_size,
                              hipStream_t stream) {
  const float* p  = (const float*)d_in[0];
  const float* x  = (const float*)d_in[1];
  const float* W0 = (const float*)d_in[2];
  const float* b0 = (const float*)d_in[3];
  const float* W1 = (const float*)d_in[4];
  const float* b1 = (const float*)d_in[5];
  const float* W2 = (const float*)d_in[6];
  const float* b2 = (const float*)d_in[7];
  float* out = (float*)d_out;

  char* w = (char*)d_ws;
  float*  coef = (float*)w;      w += 8192;
  __bf16* A0   = (__bf16*)w;     w += (size_t)B_SZ * K0P * 2;
  __bf16* A1   = (__bf16*)w;     w += (size_t)B_SZ * K12 * 2;
  __bf16* A2   = (__bf16*)w;     w += (size_t)B_SZ * K12 * 2;
  __bf16* WT0  = (__bf16*)w;     w += (size_t)HID * K0P * 2;
  __bf16* WT1  = (__bf16*)w;     w += (size_t)HID * K12 * 2;
  __bf16* WT2  = (__bf16*)w;     w += (size_t)N2P * K12 * 2;
  float*  P    = (float*)w;      // SPLIT * 512 * 512 * 4 = 4 MB

  setup_kernel<<<B_SZ + 608, 256, 0, stream>>>(p, x, W0, W1, W2, coef, A0,
                                               WT0, WT1, WT2);

  // L0: A0(512x1536) @ WT0^T -> P -> A1 (bf16 512x2048)
  gemm_splitk<<<dim3(8, 16, SPLIT), 256, 0, stream>>>(A0, WT0, P, K0P, HID,
                                                      K0P / SPLIT);
  epilogue_kernel<1, HID><<<B_SZ * HID / 256, 256, 0, stream>>>(P, b0, coef,
                                                                A1, HID);

  // L1: A1(512x2048) @ WT1^T -> P -> A2 (bf16 512x2048)
  gemm_splitk<<<dim3(8, 16, SPLIT), 256, 0, stream>>>(A1, WT1, P, K12, HID,
                                                      K12 / SPLIT);
  epilogue_kernel<1, HID><<<B_SZ * HID / 256, 256, 0, stream>>>(P, b1, coef,
                                                                A2, HID);

  // L2: A2(512x2048) @ WT2^T -> P -> out (fp32 512x311)
  gemm_splitk<<<dim3(N2P / 64, 16, SPLIT), 256, 0, stream>>>(A2, WT2, P, K12,
                                                             N2P, K12 / SPLIT);
  epilogue_kernel<0, N2P><<<B_SZ * N2P / 256, 256, 0, stream>>>(P, b2, coef,
                                                                out, OUT_F);
}